// Round 1
// baseline (367.658 us; speedup 1.0000x reference)
//
#include <hip/hip_runtime.h>
#include <hip/hip_bf16.h>

// Problem: per-image standardization, input (64, 512, 512, 3) fp32.
// Per image N = 512*512*3 = 786432 floats = 196608 float4.
// Geometry: 32 blocks/image x 256 threads; 6144 float4/block; 24 float4/thread.

#define N_IMG 64
#define ELEMS_PER_IMG 786432
#define VEC4_PER_IMG 196608
#define BLOCKS_PER_IMG 32
#define THREADS 256
#define VEC4_PER_BLOCK (VEC4_PER_IMG / BLOCKS_PER_IMG)   // 6144
#define VEC4_PER_THREAD (VEC4_PER_BLOCK / THREADS)       // 24

__global__ __launch_bounds__(THREADS) void std_partial_reduce(
    const float4* __restrict__ in, float* __restrict__ partials) {
    const int img = blockIdx.x / BLOCKS_PER_IMG;
    const int blk = blockIdx.x % BLOCKS_PER_IMG;
    const float4* base =
        in + (size_t)img * VEC4_PER_IMG + (size_t)blk * VEC4_PER_BLOCK;

    float s = 0.f, sq = 0.f;
#pragma unroll
    for (int i = 0; i < VEC4_PER_THREAD; ++i) {
        float4 v = base[threadIdx.x + i * THREADS];
        s += (v.x + v.y) + (v.z + v.w);
        sq += (v.x * v.x + v.y * v.y) + (v.z * v.z + v.w * v.w);
    }

    // wave64 reduce
#pragma unroll
    for (int off = 32; off > 0; off >>= 1) {
        s += __shfl_down(s, off);
        sq += __shfl_down(sq, off);
    }
    __shared__ float ss[4], ssq[4];
    const int lane = threadIdx.x & 63;
    const int wave = threadIdx.x >> 6;
    if (lane == 0) { ss[wave] = s; ssq[wave] = sq; }
    __syncthreads();
    if (threadIdx.x == 0) {
        float ts = (ss[0] + ss[1]) + (ss[2] + ss[3]);
        float tq = (ssq[0] + ssq[1]) + (ssq[2] + ssq[3]);
        partials[(size_t)blockIdx.x * 2] = ts;
        partials[(size_t)blockIdx.x * 2 + 1] = tq;
    }
}

__global__ __launch_bounds__(64) void std_stats(
    const float* __restrict__ partials, float* __restrict__ stats) {
    const int img = blockIdx.x;
    const int t = threadIdx.x;  // 0..63
    float s = 0.f, sq = 0.f;
    if (t < BLOCKS_PER_IMG) {
        s = partials[(size_t)(img * BLOCKS_PER_IMG + t) * 2];
        sq = partials[(size_t)(img * BLOCKS_PER_IMG + t) * 2 + 1];
    }
#pragma unroll
    for (int off = 32; off > 0; off >>= 1) {
        s += __shfl_down(s, off);
        sq += __shfl_down(sq, off);
    }
    if (t == 0) {
        const float invN = 1.0f / (float)ELEMS_PER_IMG;
        float mean = s * invN;
        float var = sq * invN - mean * mean;
        var = fmaxf(var, 0.0f);
        float sd = sqrtf(var);
        float min_sd = 1.0f / sqrtf((float)ELEMS_PER_IMG);  // TF clamp
        sd = fmaxf(sd, min_sd);
        stats[img * 2] = mean;
        stats[img * 2 + 1] = 1.0f / sd;
    }
}

__global__ __launch_bounds__(THREADS) void std_normalize(
    const float4* __restrict__ in, float4* __restrict__ out,
    const float* __restrict__ stats) {
    const int img = blockIdx.x / BLOCKS_PER_IMG;
    const int blk = blockIdx.x % BLOCKS_PER_IMG;
    const float mean = stats[img * 2];
    const float inv = stats[img * 2 + 1];
    const size_t base =
        (size_t)img * VEC4_PER_IMG + (size_t)blk * VEC4_PER_BLOCK;
#pragma unroll
    for (int i = 0; i < VEC4_PER_THREAD; ++i) {
        size_t idx = base + threadIdx.x + i * THREADS;
        float4 v = in[idx];
        float4 r;
        r.x = (v.x - mean) * inv;
        r.y = (v.y - mean) * inv;
        r.z = (v.z - mean) * inv;
        r.w = (v.w - mean) * inv;
        out[idx] = r;
    }
}

extern "C" void kernel_launch(void* const* d_in, const int* in_sizes, int n_in,
                              void* d_out, int out_size, void* d_ws, size_t ws_size,
                              hipStream_t stream) {
    const float4* in = (const float4*)d_in[0];
    float4* out = (float4*)d_out;
    // ws layout: [0 .. 4096) partial sums (2048 blocks x {sum,sumsq}),
    //            [4096 .. 4224) per-image {mean, inv_std}
    float* partials = (float*)d_ws;
    float* stats = partials + (size_t)N_IMG * BLOCKS_PER_IMG * 2;

    std_partial_reduce<<<N_IMG * BLOCKS_PER_IMG, THREADS, 0, stream>>>(in, partials);
    std_stats<<<N_IMG, 64, 0, stream>>>(partials, stats);
    std_normalize<<<N_IMG * BLOCKS_PER_IMG, THREADS, 0, stream>>>(in, out, stats);
}

// Round 2
// 359.912 us; speedup vs baseline: 1.0215x; 1.0215x over previous
//
#include <hip/hip_runtime.h>
#include <hip/hip_bf16.h>

// Per-image standardization, input (64, 512, 512, 3) fp32.
// Per image N = 512*512*3 = 786432 floats = 196608 float4.
// 32 blocks/image x 256 threads; 6144 float4/block; 24 float4/thread.

#define N_IMG 64
#define ELEMS_PER_IMG 786432
#define VEC4_PER_IMG 196608
#define BLOCKS_PER_IMG 32
#define THREADS 256
#define VEC4_PER_BLOCK (VEC4_PER_IMG / BLOCKS_PER_IMG)   // 6144
#define VEC4_PER_THREAD (VEC4_PER_BLOCK / THREADS)       // 24

typedef float v4f __attribute__((ext_vector_type(4)));

// Pass 1: per-block {sum, sumsq} partials.
__global__ __launch_bounds__(THREADS) void std_partial_reduce(
    const v4f* __restrict__ in, float2* __restrict__ partials) {
    const int img = blockIdx.x / BLOCKS_PER_IMG;
    const int blk = blockIdx.x % BLOCKS_PER_IMG;
    const v4f* base =
        in + (size_t)img * VEC4_PER_IMG + (size_t)blk * VEC4_PER_BLOCK;

    float s = 0.f, sq = 0.f;
#pragma unroll
    for (int i = 0; i < VEC4_PER_THREAD; ++i) {
        v4f v = base[threadIdx.x + i * THREADS];
        s += (v.x + v.y) + (v.z + v.w);
        sq = fmaf(v.x, v.x, sq);
        sq = fmaf(v.y, v.y, sq);
        sq = fmaf(v.z, v.z, sq);
        sq = fmaf(v.w, v.w, sq);
    }

#pragma unroll
    for (int off = 32; off > 0; off >>= 1) {
        s += __shfl_down(s, off);
        sq += __shfl_down(sq, off);
    }
    __shared__ float ss[4], ssq[4];
    const int lane = threadIdx.x & 63;
    const int wave = threadIdx.x >> 6;
    if (lane == 0) { ss[wave] = s; ssq[wave] = sq; }
    __syncthreads();
    if (threadIdx.x == 0) {
        float2 p;
        p.x = (ss[0] + ss[1]) + (ss[2] + ss[3]);
        p.y = (ssq[0] + ssq[1]) + (ssq[2] + ssq[3]);
        partials[blockIdx.x] = p;
    }
}

// Pass 2: each block redundantly reduces its image's 32 partials (cheap,
// L2-served), then normalizes its chunk. Output stores are non-temporal so
// the write stream doesn't evict the L3-resident input we're re-reading.
__global__ __launch_bounds__(THREADS) void std_normalize(
    const v4f* __restrict__ in, v4f* __restrict__ out,
    const float2* __restrict__ partials) {
    const int img = blockIdx.x / BLOCKS_PER_IMG;
    const int blk = blockIdx.x % BLOCKS_PER_IMG;

    __shared__ float s_mean, s_inv;
    if (threadIdx.x < 64) {
        float s = 0.f, sq = 0.f;
        if (threadIdx.x < BLOCKS_PER_IMG) {
            float2 p = partials[img * BLOCKS_PER_IMG + threadIdx.x];
            s = p.x;
            sq = p.y;
        }
#pragma unroll
        for (int off = 16; off > 0; off >>= 1) {
            s += __shfl_down(s, off);
            sq += __shfl_down(sq, off);
        }
        if (threadIdx.x == 0) {
            const float invN = 1.0f / (float)ELEMS_PER_IMG;
            float mean = s * invN;
            float var = fmaxf(sq * invN - mean * mean, 0.0f);
            float sd = sqrtf(var);
            float min_sd = 1.0f / sqrtf((float)ELEMS_PER_IMG);  // TF clamp
            sd = fmaxf(sd, min_sd);
            s_mean = mean;
            s_inv = 1.0f / sd;
        }
    }
    __syncthreads();
    const float mean = s_mean;
    const float inv = s_inv;

    const size_t base =
        (size_t)img * VEC4_PER_IMG + (size_t)blk * VEC4_PER_BLOCK;
#pragma unroll
    for (int i = 0; i < VEC4_PER_THREAD; ++i) {
        size_t idx = base + threadIdx.x + i * THREADS;
        v4f v = in[idx];
        v4f r;
        r.x = (v.x - mean) * inv;
        r.y = (v.y - mean) * inv;
        r.z = (v.z - mean) * inv;
        r.w = (v.w - mean) * inv;
        __builtin_nontemporal_store(r, &out[idx]);
    }
}

extern "C" void kernel_launch(void* const* d_in, const int* in_sizes, int n_in,
                              void* d_out, int out_size, void* d_ws, size_t ws_size,
                              hipStream_t stream) {
    const v4f* in = (const v4f*)d_in[0];
    v4f* out = (v4f*)d_out;
    float2* partials = (float2*)d_ws;  // 2048 x float2 = 16 KiB

    std_partial_reduce<<<N_IMG * BLOCKS_PER_IMG, THREADS, 0, stream>>>(in, partials);
    std_normalize<<<N_IMG * BLOCKS_PER_IMG, THREADS, 0, stream>>>(in, out, partials);
}